// Round 7
// baseline (882.521 us; speedup 1.0000x reference)
//
#include <hip/hip_runtime.h>

#define NN 100000
#define EE 3200000
#define NF 256
#define NH 128
#define NC 16
#define NBKT 391       // buckets of 256 dst nodes: ceil(100000/256)
#define BSZ 256        // nodes per bucket
#define BCAP 9600      // staging capacity per bucket (mean 8192, +15.5 sigma)
#define CHUNK 4096     // edges per k_bucket block

typedef __bf16 bf16;
typedef bf16 bf16x2 __attribute__((ext_vector_type(2)));
typedef bf16 bf16x8 __attribute__((ext_vector_type(8)));
typedef float f32x4 __attribute__((ext_vector_type(4)));

// ---------------- CSR build: bucket partition + per-bucket LDS sort ----------------

__global__ void k_init(int* __restrict__ bucket_cursor, int2* __restrict__ edges) {
    int t = threadIdx.x;
    if (t < NBKT) bucket_cursor[t] = t * BCAP;
    if (t >= 496) edges[EE + t - 496] = make_int2(0, 0);  // 16-record pad for spmm overrun
}

// Pass 1: partition edges into NBKT staging regions, LDS-binned so global
// writes are contiguous runs per bucket instead of 8B scatter.
__global__ __launch_bounds__(512) void k_bucket(const int* __restrict__ src,
                                                const int* __restrict__ dst,
                                                const float* __restrict__ ew,
                                                int* __restrict__ bucket_cursor,
                                                int2* __restrict__ staged) {
    __shared__ int2 recs[CHUNK];              // 32 KB
    __shared__ unsigned short bkt[CHUNK];     // 8 KB
    __shared__ int cnt[NBKT], start[NBKT + 1], cur[NBKT], gbase[NBKT];
    __shared__ int sc[512];
    int t = threadIdx.x;
    int base = blockIdx.x * CHUNK;
    int n = EE - base; if (n > CHUNK) n = CHUNK;
    if (t < NBKT) cnt[t] = 0;
    __syncthreads();
    for (int i = t; i < n; i += 512) {
        atomicAdd(&cnt[dst[base + i] >> 8], 1);
    }
    __syncthreads();
    sc[t] = (t < NBKT) ? cnt[t] : 0;
    __syncthreads();
    for (int off = 1; off < 512; off <<= 1) {
        int v = (t >= off) ? sc[t - off] : 0;
        __syncthreads();
        sc[t] += v;
        __syncthreads();
    }
    if (t < NBKT) { start[t] = sc[t] - cnt[t]; cur[t] = sc[t] - cnt[t]; }
    if (t == 0) start[NBKT] = sc[511];
    __syncthreads();
    for (int i = t; i < n; i += 512) {
        int d = dst[base + i];
        int b = d >> 8;
        int p = atomicAdd(&cur[b], 1);
        recs[p] = make_int2(src[base + i] | ((d & 255) << 17), __float_as_int(ew[base + i]));
        bkt[p] = (unsigned short)b;
    }
    __syncthreads();
    if (t < NBKT) gbase[t] = atomicAdd(&bucket_cursor[t], start[t + 1] - start[t]);
    __syncthreads();
    for (int i = t; i < n; i += 512) {
        int b = bkt[i];
        staged[gbase[b] + (i - start[b])] = recs[i];
    }
}

// Exclusive scan of per-bucket counts -> global base of each bucket in edges[].
__global__ void k_bscan(const int* __restrict__ bucket_cursor,
                        int* __restrict__ bucket_base, int* __restrict__ row_off) {
    __shared__ int s[512];
    int t = threadIdx.x;
    int v = (t < NBKT) ? (bucket_cursor[t] - t * BCAP) : 0;
    s[t] = v;
    __syncthreads();
    for (int off = 1; off < 512; off <<= 1) {
        int x = (t >= off) ? s[t - off] : 0;
        __syncthreads();
        s[t] += x;
        __syncthreads();
    }
    if (t < NBKT) bucket_base[t] = s[t] - v;
    if (t == 0) { bucket_base[NBKT] = EE; row_off[NN] = EE; }
}

// One block per bucket: LDS counting sort. 512 threads, 79.9 KB LDS ->
// 2 blocks/CU (16 waves), 391 blocks ~ one balanced round over 256 CUs.
__global__ __launch_bounds__(512) void k_sort(const int2* __restrict__ staged,
                                              const int* __restrict__ bucket_cursor,
                                              const int* __restrict__ bucket_base,
                                              int* __restrict__ row_off,
                                              int2* __restrict__ edges) {
    __shared__ int2 lrec[BCAP];               // 76.8 KB
    __shared__ int lcnt[BSZ], lstart[BSZ], lcur[BSZ];
    int t = threadIdx.x;
    int b = blockIdx.x;
    int n = bucket_cursor[b] - b * BCAP;
    int gb = bucket_base[b];
    const int2* sp = staged + (size_t)b * BCAP;
    if (t < BSZ) lcnt[t] = 0;
    __syncthreads();
    for (int i = t; i < n; i += 512) {
        int2 r = sp[i];
        lrec[i] = r;
        atomicAdd(&lcnt[r.x >> 17], 1);
    }
    __syncthreads();
    if (t < BSZ) lstart[t] = lcnt[t];
    __syncthreads();
    for (int off = 1; off < BSZ; off <<= 1) {
        int v = 0;
        if (t < BSZ && t >= off) v = lstart[t - off];
        __syncthreads();
        if (t < BSZ) lstart[t] += v;
        __syncthreads();
    }
    if (t < BSZ) {
        int ex = lstart[t] - lcnt[t];        // exclusive within-bucket start
        lcur[t] = ex;
        int node = (b << 8) + t;
        if (node < NN) row_off[node] = gb + ex;
    }
    __syncthreads();
    for (int i = t; i < n; i += 512) {
        int2 r = lrec[i];
        int d = r.x >> 17;
        int p = atomicAdd(&lcur[d], 1);
        edges[gb + p] = make_int2(r.x & 0x1FFFF, r.y);
    }
}

// ---------------- layer 1: x @ W1 (bf16 MFMA) ----------------

__global__ void k_cvtW1(const float* __restrict__ W1, bf16* __restrict__ W1T) {
    int i = blockIdx.x * 256 + threadIdx.x;  // 32768 elems, W1 is [NF][NH]
    int k = i >> 7, n = i & 127;
    W1T[n * NF + k] = (bf16)W1[i];           // W1T: [NH][NF]
}

__global__ __launch_bounds__(256, 1) void k_gemm1(const float* __restrict__ x,
                                                  const bf16* __restrict__ W1T,
                                                  bf16* __restrict__ h0) {
    int lane = threadIdx.x & 63;
    int wid = threadIdx.x >> 6;
    int m = lane & 15;     // A row / D col within 16-tile
    int kg = lane >> 4;    // k-group 0..3
    int row = blockIdx.x * 64 + wid * 16 + m;
    bool in = (row < NN);
    const float* xr = x + (size_t)row * NF;

    bf16x8 a[8];
#pragma unroll
    for (int kt = 0; kt < 8; kt++) {
        int k0 = kt * 32 + kg * 8;
        float4 u = in ? *(const float4*)(xr + k0)     : make_float4(0.f, 0.f, 0.f, 0.f);
        float4 v = in ? *(const float4*)(xr + k0 + 4) : make_float4(0.f, 0.f, 0.f, 0.f);
        bf16x8 av = { (bf16)u.x, (bf16)u.y, (bf16)u.z, (bf16)u.w,
                      (bf16)v.x, (bf16)v.y, (bf16)v.z, (bf16)v.w };
        a[kt] = av;
    }

    f32x4 acc[8] = {};
#pragma unroll
    for (int ct = 0; ct < 8; ct++) {
        const bf16* bp = W1T + (size_t)(ct * 16 + m) * NF + kg * 8;
#pragma unroll
        for (int kt = 0; kt < 8; kt++) {
            bf16x8 b = *(const bf16x8*)(bp + kt * 32);
            acc[ct] = __builtin_amdgcn_mfma_f32_16x16x32_bf16(a[kt], b, acc[ct], 0, 0, 0);
        }
    }

    // D layout: col = lane&15, row = (lane>>4)*4 + reg
    int rbase = blockIdx.x * 64 + wid * 16 + kg * 4;
#pragma unroll
    for (int ct = 0; ct < 8; ct++) {
        int col = ct * 16 + m;
#pragma unroll
        for (int r = 0; r < 4; r++) {
            int rr = rbase + r;
            if (rr < NN) h0[(size_t)rr * NH + col] = (bf16)acc[ct][r];
        }
    }
}

// ---------------- spmm1: h = relu(A @ h0 + b1) ----------------
// one wave per node. Edge records come in via the SCALAR pipe (s_load);
// OOB records (up to 15 past row end) get w=0 AND src=0 via scalar cselect.

__global__ __launch_bounds__(256) void k_spmm1(const int* __restrict__ row_off,
                                               const int2* __restrict__ edges,
                                               const bf16* __restrict__ h0,
                                               const float* __restrict__ b1,
                                               bf16* __restrict__ h) {
    int wid = __builtin_amdgcn_readfirstlane(threadIdx.x >> 6);
    int node = blockIdx.x * 4 + wid;               // wave-uniform, always < NN
    int lane = threadIdx.x & 63;
    int s = row_off[node], e = row_off[node + 1];  // uniform -> s_load

    const char* h0b = (const char*)h0;
    unsigned loff = (unsigned)lane * 4u;           // loop-invariant lane offset

    float ax[8], ay[8];
#pragma unroll
    for (int j = 0; j < 8; j++) { ax[j] = 0.f; ay[j] = 0.f; }

    for (int i = s; i < e; i += 16) {
        int2 q[16];
#pragma unroll
        for (int j = 0; j < 16; j++) q[j] = edges[i + j];   // uniform -> s_load
        unsigned sv[16];
        float wv[16];
#pragma unroll
        for (int j = 0; j < 16; j++) {
            bool v = (i + j) < e;                            // scalar cmp
            sv[j] = v ? (unsigned)q[j].x : 0u;               // s_cselect
            wv[j] = v ? __int_as_float(q[j].y) : 0.f;        // s_cselect
        }
        unsigned dv[16];
#pragma unroll
        for (int j = 0; j < 16; j++) {
            const char* p = h0b + (((size_t)sv[j] << 8) + loff);
            dv[j] = *(const unsigned*)p;                     // 16 gathers in flight
        }
#pragma unroll
        for (int j = 0; j < 16; j++) {
            float h0f = __int_as_float(dv[j] << 16);
            float h1f = __int_as_float(dv[j] & 0xffff0000u);
            ax[j & 7] += wv[j] * h0f;
            ay[j & 7] += wv[j] * h1f;
        }
    }
    float sx = ((ax[0] + ax[1]) + (ax[2] + ax[3])) + ((ax[4] + ax[5]) + (ax[6] + ax[7]));
    float sy = ((ay[0] + ay[1]) + (ay[2] + ay[3])) + ((ay[4] + ay[5]) + (ay[6] + ay[7]));
    sx = fmaxf(sx + b1[lane * 2],     0.f);
    sy = fmaxf(sy + b1[lane * 2 + 1], 0.f);
    bf16x2 o = { (bf16)sx, (bf16)sy };
    *(bf16x2*)(h + (size_t)node * NH + lane * 2) = o;
}

// ---------------- gemm2: g = h @ W2 (bf16 out), one thread per row ----------------

__global__ __launch_bounds__(256) void k_gemm2(const bf16* __restrict__ h,
                                               const float* __restrict__ W2,
                                               bf16* __restrict__ g) {
    __shared__ float sW[NH * NC];
    int t = threadIdx.x;
    for (int i = t; i < NH * NC; i += 256) sW[i] = W2[i];
    __syncthreads();
    int row = blockIdx.x * 256 + t;
    if (row >= NN) return;
    const bf16* hr = h + (size_t)row * NH;
    float acc[NC] = {};
    for (int kc = 0; kc < NH / 8; kc++) {
        bf16x8 hv = *(const bf16x8*)(hr + kc * 8);
#pragma unroll
        for (int j = 0; j < 8; j++) {
            float hx = (float)hv[j];
            const float* wr = &sW[(kc * 8 + j) * NC];
#pragma unroll
            for (int c = 0; c < NC; c++) acc[c] += hx * wr[c];
        }
    }
    bf16x8 o0 = { (bf16)acc[0], (bf16)acc[1], (bf16)acc[2],  (bf16)acc[3],
                  (bf16)acc[4], (bf16)acc[5], (bf16)acc[6],  (bf16)acc[7] };
    bf16x8 o1 = { (bf16)acc[8], (bf16)acc[9], (bf16)acc[10], (bf16)acc[11],
                  (bf16)acc[12], (bf16)acc[13], (bf16)acc[14], (bf16)acc[15] };
    bf16* gr = g + (size_t)row * NC;
    *(bf16x8*)gr = o0;
    *(bf16x8*)(gr + 8) = o1;
}

// ---------------- spmm2 + bias + log_softmax fused ----------------
// one wave per node: lane = sub*16 + c. Edge records s_loaded wave-uniform
// (16 per iter); each subgroup selects its record from scalars via 3 cndmask;
// 16 g-row gathers (32 B each, L2-resident) in flight.

__global__ __launch_bounds__(256) void k_spmm2(const int* __restrict__ row_off,
                                               const int2* __restrict__ edges,
                                               const bf16* __restrict__ g,
                                               const float* __restrict__ b2,
                                               float* __restrict__ out) {
    int wid = __builtin_amdgcn_readfirstlane(threadIdx.x >> 6);
    int node = blockIdx.x * 4 + wid;               // wave-uniform, always < NN
    int lane = threadIdx.x & 63;
    int c = lane & 15, sub = lane >> 4;
    int s = row_off[node], e = row_off[node + 1];  // uniform -> s_load
    const unsigned short* gbp = (const unsigned short*)g;
    bool sel1 = (sub & 1) != 0;
    bool sel2 = (sub & 2) != 0;

    float acc[4] = { 0.f, 0.f, 0.f, 0.f };
    for (int i = s; i < e; i += 16) {
        int2 q[16];
#pragma unroll
        for (int j = 0; j < 16; j++) q[j] = edges[i + j];   // uniform -> s_load
#pragma unroll
        for (int k = 0; k < 4; k++) {
            unsigned a01 = sel1 ? (unsigned)q[4 * k + 1].x : (unsigned)q[4 * k].x;
            unsigned a23 = sel1 ? (unsigned)q[4 * k + 3].x : (unsigned)q[4 * k + 2].x;
            unsigned sx = sel2 ? a23 : a01;
            float w01 = sel1 ? __int_as_float(q[4 * k + 1].y) : __int_as_float(q[4 * k].y);
            float w23 = sel1 ? __int_as_float(q[4 * k + 3].y) : __int_as_float(q[4 * k + 2].y);
            float w = sel2 ? w23 : w01;
            bool valid = (i + 4 * k + sub) < e;
            w = valid ? w : 0.f;
            sx = valid ? sx : 0u;
            unsigned hv = gbp[sx * NC + c];
            acc[k] += w * __int_as_float(hv << 16);
        }
    }
    float a = (acc[0] + acc[1]) + (acc[2] + acc[3]);
    a += __shfl_xor(a, 16);
    a += __shfl_xor(a, 32);
    a += b2[c];
    float m = a;
#pragma unroll
    for (int off = 1; off < 16; off <<= 1) m = fmaxf(m, __shfl_xor(m, off));
    float ex = __expf(a - m);
    float sum = ex;
#pragma unroll
    for (int off = 1; off < 16; off <<= 1) sum += __shfl_xor(sum, off);
    float r = a - m - __logf(sum);
    if (sub == 0) out[(size_t)node * NC + c] = r;
}

// ---------------- launch ----------------

extern "C" void kernel_launch(void* const* d_in, const int* in_sizes, int n_in,
                              void* d_out, int out_size, void* d_ws, size_t ws_size,
                              hipStream_t stream) {
    const float* x  = (const float*)d_in[0];
    const float* W1 = (const float*)d_in[1];
    const float* b1 = (const float*)d_in[2];
    const float* W2 = (const float*)d_in[3];
    const float* b2 = (const float*)d_in[4];
    const float* ew = (const float*)d_in[5];
    const int* src  = (const int*)d_in[6];
    const int* dst  = (const int*)d_in[7];
    float* out = (float*)d_out;

    char* ws = (char*)d_ws;
    bf16*  h0      = (bf16*)(ws + 0);              // 25,600,000
    bf16*  h       = (bf16*)(ws + 25600000);       // 25,600,000
    bf16*  g       = (bf16*)(ws + 51200000);       // NN*NC*2 = 3,200,000
    int*   row_off = (int*)(ws + 54400000);        // (NN+1)*4 = 400,004
    int*   bucket_cursor = (int*)(ws + 54800016);  // 1,564
    int*   bucket_base   = (int*)(ws + 54801584);  // 1,568
    int2*  edges   = (int2*)(ws + 54803168);       // EE*8 + 128 pad = 25,600,128
    bf16*  W1T     = (bf16*)(ws + 80403296);       // 65,536 -> end 80,468,832
    // staged aliases h0 + low part of h: dead before k_gemm1 writes h0
    int2*  staged  = (int2*)(ws + 0);              // NBKT*BCAP*8 = 30,028,800

    // CSR build
    k_init<<<1, 512, 0, stream>>>(bucket_cursor, edges);
    k_bucket<<<(EE + CHUNK - 1) / CHUNK, 512, 0, stream>>>(src, dst, ew, bucket_cursor, staged);
    k_bscan<<<1, 512, 0, stream>>>(bucket_cursor, bucket_base, row_off);
    k_sort<<<NBKT, 512, 0, stream>>>(staged, bucket_cursor, bucket_base, row_off, edges);

    // layer 1
    k_cvtW1<<<(NF * NH) / 256, 256, 0, stream>>>(W1, W1T);
    k_gemm1<<<(NN + 63) / 64, 256, 0, stream>>>(x, W1T, h0);
    k_spmm1<<<NN / 4, 256, 0, stream>>>(row_off, edges, h0, b1, h);

    // layer 2
    k_gemm2<<<(NN + 255) / 256, 256, 0, stream>>>(h, W2, g);
    k_spmm2<<<NN / 4, 256, 0, stream>>>(row_off, edges, g, b2, out);
}

// Round 8
// 488.634 us; speedup vs baseline: 1.8061x; 1.8061x over previous
//
#include <hip/hip_runtime.h>

#define NN 100000
#define EE 3200000
#define NF 256
#define NH 128
#define NC 16
#define NBKT 391       // buckets of 256 dst nodes: ceil(100000/256)
#define BSZ 256        // nodes per bucket
#define BCAP 9600      // staging capacity per bucket (mean 8192, +15.5 sigma)
#define CHUNK 4096     // edges per k_bucket block

typedef __bf16 bf16;
typedef bf16 bf16x2 __attribute__((ext_vector_type(2)));
typedef bf16 bf16x8 __attribute__((ext_vector_type(8)));
typedef float f32x4 __attribute__((ext_vector_type(4)));

// ---------------- CSR build: bucket partition + per-bucket LDS sort ----------------

__global__ void k_init(int* __restrict__ bucket_cursor, int2* __restrict__ edges) {
    int t = threadIdx.x;
    if (t < NBKT) bucket_cursor[t] = t * BCAP;
    if (t >= 496) edges[EE + t - 496] = make_int2(0, 0);  // 16-record pad for spmm overrun
}

// Pass 1: partition edges into NBKT staging regions, LDS-binned so global
// writes are contiguous runs per bucket instead of 8B scatter.
__global__ __launch_bounds__(512) void k_bucket(const int* __restrict__ src,
                                                const int* __restrict__ dst,
                                                const float* __restrict__ ew,
                                                int* __restrict__ bucket_cursor,
                                                int2* __restrict__ staged) {
    __shared__ int2 recs[CHUNK];              // 32 KB
    __shared__ unsigned short bkt[CHUNK];     // 8 KB
    __shared__ int cnt[NBKT], start[NBKT + 1], cur[NBKT], gbase[NBKT];
    __shared__ int sc[512];
    int t = threadIdx.x;
    int base = blockIdx.x * CHUNK;
    int n = EE - base; if (n > CHUNK) n = CHUNK;
    if (t < NBKT) cnt[t] = 0;
    __syncthreads();
    for (int i = t; i < n; i += 512) {
        atomicAdd(&cnt[dst[base + i] >> 8], 1);
    }
    __syncthreads();
    sc[t] = (t < NBKT) ? cnt[t] : 0;
    __syncthreads();
    for (int off = 1; off < 512; off <<= 1) {
        int v = (t >= off) ? sc[t - off] : 0;
        __syncthreads();
        sc[t] += v;
        __syncthreads();
    }
    if (t < NBKT) { start[t] = sc[t] - cnt[t]; cur[t] = sc[t] - cnt[t]; }
    if (t == 0) start[NBKT] = sc[511];
    __syncthreads();
    for (int i = t; i < n; i += 512) {
        int d = dst[base + i];
        int b = d >> 8;
        int p = atomicAdd(&cur[b], 1);
        recs[p] = make_int2(src[base + i] | ((d & 255) << 17), __float_as_int(ew[base + i]));
        bkt[p] = (unsigned short)b;
    }
    __syncthreads();
    if (t < NBKT) gbase[t] = atomicAdd(&bucket_cursor[t], start[t + 1] - start[t]);
    __syncthreads();
    for (int i = t; i < n; i += 512) {
        int b = bkt[i];
        staged[gbase[b] + (i - start[b])] = recs[i];
    }
}

// Exclusive scan of per-bucket counts -> global base of each bucket in edges[].
__global__ void k_bscan(const int* __restrict__ bucket_cursor,
                        int* __restrict__ bucket_base, int* __restrict__ row_off) {
    __shared__ int s[512];
    int t = threadIdx.x;
    int v = (t < NBKT) ? (bucket_cursor[t] - t * BCAP) : 0;
    s[t] = v;
    __syncthreads();
    for (int off = 1; off < 512; off <<= 1) {
        int x = (t >= off) ? s[t - off] : 0;
        __syncthreads();
        s[t] += x;
        __syncthreads();
    }
    if (t < NBKT) bucket_base[t] = s[t] - v;
    if (t == 0) { bucket_base[NBKT] = EE; row_off[NN] = EE; }
}

// One block per bucket: LDS counting sort. 512 threads, 79.9 KB LDS ->
// 2 blocks/CU (16 waves), 391 blocks ~ one balanced round over 256 CUs.
__global__ __launch_bounds__(512) void k_sort(const int2* __restrict__ staged,
                                              const int* __restrict__ bucket_cursor,
                                              const int* __restrict__ bucket_base,
                                              int* __restrict__ row_off,
                                              int2* __restrict__ edges) {
    __shared__ int2 lrec[BCAP];               // 76.8 KB
    __shared__ int lcnt[BSZ], lstart[BSZ], lcur[BSZ];
    int t = threadIdx.x;
    int b = blockIdx.x;
    int n = bucket_cursor[b] - b * BCAP;
    int gb = bucket_base[b];
    const int2* sp = staged + (size_t)b * BCAP;
    if (t < BSZ) lcnt[t] = 0;
    __syncthreads();
    for (int i = t; i < n; i += 512) {
        int2 r = sp[i];
        lrec[i] = r;
        atomicAdd(&lcnt[r.x >> 17], 1);
    }
    __syncthreads();
    if (t < BSZ) lstart[t] = lcnt[t];
    __syncthreads();
    for (int off = 1; off < BSZ; off <<= 1) {
        int v = 0;
        if (t < BSZ && t >= off) v = lstart[t - off];
        __syncthreads();
        if (t < BSZ) lstart[t] += v;
        __syncthreads();
    }
    if (t < BSZ) {
        int ex = lstart[t] - lcnt[t];        // exclusive within-bucket start
        lcur[t] = ex;
        int node = (b << 8) + t;
        if (node < NN) row_off[node] = gb + ex;
    }
    __syncthreads();
    for (int i = t; i < n; i += 512) {
        int2 r = lrec[i];
        int d = r.x >> 17;
        int p = atomicAdd(&lcur[d], 1);
        edges[gb + p] = make_int2(r.x & 0x1FFFF, r.y);
    }
}

// ---------------- layer 1: x @ W1 (bf16 MFMA) ----------------

__global__ void k_cvtW1(const float* __restrict__ W1, bf16* __restrict__ W1T) {
    int i = blockIdx.x * 256 + threadIdx.x;  // 32768 elems, W1 is [NF][NH]
    int k = i >> 7, n = i & 127;
    W1T[n * NF + k] = (bf16)W1[i];           // W1T: [NH][NF]
}

__global__ __launch_bounds__(256, 1) void k_gemm1(const float* __restrict__ x,
                                                  const bf16* __restrict__ W1T,
                                                  bf16* __restrict__ h0) {
    int lane = threadIdx.x & 63;
    int wid = threadIdx.x >> 6;
    int m = lane & 15;     // A row / D col within 16-tile
    int kg = lane >> 4;    // k-group 0..3
    int row = blockIdx.x * 64 + wid * 16 + m;
    bool in = (row < NN);
    const float* xr = x + (size_t)row * NF;

    bf16x8 a[8];
#pragma unroll
    for (int kt = 0; kt < 8; kt++) {
        int k0 = kt * 32 + kg * 8;
        float4 u = in ? *(const float4*)(xr + k0)     : make_float4(0.f, 0.f, 0.f, 0.f);
        float4 v = in ? *(const float4*)(xr + k0 + 4) : make_float4(0.f, 0.f, 0.f, 0.f);
        bf16x8 av = { (bf16)u.x, (bf16)u.y, (bf16)u.z, (bf16)u.w,
                      (bf16)v.x, (bf16)v.y, (bf16)v.z, (bf16)v.w };
        a[kt] = av;
    }

    f32x4 acc[8] = {};
#pragma unroll
    for (int ct = 0; ct < 8; ct++) {
        const bf16* bp = W1T + (size_t)(ct * 16 + m) * NF + kg * 8;
#pragma unroll
        for (int kt = 0; kt < 8; kt++) {
            bf16x8 b = *(const bf16x8*)(bp + kt * 32);
            acc[ct] = __builtin_amdgcn_mfma_f32_16x16x32_bf16(a[kt], b, acc[ct], 0, 0, 0);
        }
    }

    // D layout: col = lane&15, row = (lane>>4)*4 + reg
    int rbase = blockIdx.x * 64 + wid * 16 + kg * 4;
#pragma unroll
    for (int ct = 0; ct < 8; ct++) {
        int col = ct * 16 + m;
#pragma unroll
        for (int r = 0; r < 4; r++) {
            int rr = rbase + r;
            if (rr < NN) h0[(size_t)rr * NH + col] = (bf16)acc[ct][r];
        }
    }
}

// ---------------- spmm1: h = relu(A @ h0 + b1) ----------------
// one wave per node. Edge records come in via the SCALAR pipe (s_load);
// OOB records (up to 15 past row end) get w=0 AND src=0 via scalar cselect.

__global__ __launch_bounds__(256) void k_spmm1(const int* __restrict__ row_off,
                                               const int2* __restrict__ edges,
                                               const bf16* __restrict__ h0,
                                               const float* __restrict__ b1,
                                               bf16* __restrict__ h) {
    int wid = __builtin_amdgcn_readfirstlane(threadIdx.x >> 6);
    int node = blockIdx.x * 4 + wid;               // wave-uniform, always < NN
    int lane = threadIdx.x & 63;
    int s = row_off[node], e = row_off[node + 1];  // uniform -> s_load

    const char* h0b = (const char*)h0;
    unsigned loff = (unsigned)lane * 4u;           // loop-invariant lane offset

    float ax[8], ay[8];
#pragma unroll
    for (int j = 0; j < 8; j++) { ax[j] = 0.f; ay[j] = 0.f; }

    for (int i = s; i < e; i += 16) {
        int2 q[16];
#pragma unroll
        for (int j = 0; j < 16; j++) q[j] = edges[i + j];   // uniform -> s_load
        unsigned sv[16];
        float wv[16];
#pragma unroll
        for (int j = 0; j < 16; j++) {
            bool v = (i + j) < e;                            // scalar cmp
            sv[j] = v ? (unsigned)q[j].x : 0u;               // s_cselect
            wv[j] = v ? __int_as_float(q[j].y) : 0.f;        // s_cselect
        }
        unsigned dv[16];
#pragma unroll
        for (int j = 0; j < 16; j++) {
            const char* p = h0b + (((size_t)sv[j] << 8) + loff);
            dv[j] = *(const unsigned*)p;                     // 16 gathers in flight
        }
#pragma unroll
        for (int j = 0; j < 16; j++) {
            float h0f = __int_as_float(dv[j] << 16);
            float h1f = __int_as_float(dv[j] & 0xffff0000u);
            ax[j & 7] += wv[j] * h0f;
            ay[j & 7] += wv[j] * h1f;
        }
    }
    float sx = ((ax[0] + ax[1]) + (ax[2] + ax[3])) + ((ax[4] + ax[5]) + (ax[6] + ax[7]));
    float sy = ((ay[0] + ay[1]) + (ay[2] + ay[3])) + ((ay[4] + ay[5]) + (ay[6] + ay[7]));
    sx = fmaxf(sx + b1[lane * 2],     0.f);
    sy = fmaxf(sy + b1[lane * 2 + 1], 0.f);
    bf16x2 o = { (bf16)sx, (bf16)sy };
    *(bf16x2*)(h + (size_t)node * NH + lane * 2) = o;
}

// ---------------- gemm2: g = h @ W2 (bf16 out), one thread per row ----------------

__global__ __launch_bounds__(256) void k_gemm2(const bf16* __restrict__ h,
                                               const float* __restrict__ W2,
                                               bf16* __restrict__ g) {
    __shared__ float sW[NH * NC];
    int t = threadIdx.x;
    for (int i = t; i < NH * NC; i += 256) sW[i] = W2[i];
    __syncthreads();
    int row = blockIdx.x * 256 + t;
    if (row >= NN) return;
    const bf16* hr = h + (size_t)row * NH;
    float acc[NC] = {};
    for (int kc = 0; kc < NH / 8; kc++) {
        bf16x8 hv = *(const bf16x8*)(hr + kc * 8);
#pragma unroll
        for (int j = 0; j < 8; j++) {
            float hx = (float)hv[j];
            const float* wr = &sW[(kc * 8 + j) * NC];
#pragma unroll
            for (int c = 0; c < NC; c++) acc[c] += hx * wr[c];
        }
    }
    bf16x8 o0 = { (bf16)acc[0], (bf16)acc[1], (bf16)acc[2],  (bf16)acc[3],
                  (bf16)acc[4], (bf16)acc[5], (bf16)acc[6],  (bf16)acc[7] };
    bf16x8 o1 = { (bf16)acc[8], (bf16)acc[9], (bf16)acc[10], (bf16)acc[11],
                  (bf16)acc[12], (bf16)acc[13], (bf16)acc[14], (bf16)acc[15] };
    bf16* gr = g + (size_t)row * NC;
    *(bf16x8*)gr = o0;
    *(bf16x8*)(gr + 8) = o1;
}

// ---------------- spmm2 + bias + log_softmax fused ----------------
// one wave per node: lane = sub*16 + c; 4 subgroups x 4-deep predicated ILP
// -> 16 edges in flight. Each subgroup vector-loads its own record (16-lane
// same-address broadcast, no SGPR-array selection -> no VGPR spill).

__global__ __launch_bounds__(256) void k_spmm2(const int* __restrict__ row_off,
                                               const int2* __restrict__ edges,
                                               const bf16* __restrict__ g,
                                               const float* __restrict__ b2,
                                               float* __restrict__ out) {
    int node = (blockIdx.x * 256 + threadIdx.x) >> 6;  // 4 nodes per block
    int lane = threadIdx.x & 63;
    int c = lane & 15, sub = lane >> 4;
    int s = row_off[node], e = row_off[node + 1];
    const unsigned short* gbp = (const unsigned short*)g;

    float acc[4] = { 0.f, 0.f, 0.f, 0.f };
    for (int i = s + sub; i < e; i += 16) {
        unsigned sx[4]; float w[4];
#pragma unroll
        for (int k = 0; k < 4; k++) {
            int idx = i + 4 * k;                 // <= e+11 <= EE+11: pad covers
            int2 r = edges[idx];
            bool v = idx < e;
            sx[k] = v ? (unsigned)r.x : 0u;
            w[k]  = v ? __int_as_float(r.y) : 0.f;
        }
#pragma unroll
        for (int k = 0; k < 4; k++) {
            unsigned hv = gbp[sx[k] * NC + c];
            acc[k] += w[k] * __int_as_float(hv << 16);
        }
    }
    float a = (acc[0] + acc[1]) + (acc[2] + acc[3]);
    a += __shfl_xor(a, 16);
    a += __shfl_xor(a, 32);
    a += b2[c];
    float m = a;
#pragma unroll
    for (int off = 1; off < 16; off <<= 1) m = fmaxf(m, __shfl_xor(m, off));
    float ex = __expf(a - m);
    float sum = ex;
#pragma unroll
    for (int off = 1; off < 16; off <<= 1) sum += __shfl_xor(sum, off);
    float r = a - m - __logf(sum);
    if (sub == 0) out[(size_t)node * NC + c] = r;
}

// ---------------- launch ----------------

extern "C" void kernel_launch(void* const* d_in, const int* in_sizes, int n_in,
                              void* d_out, int out_size, void* d_ws, size_t ws_size,
                              hipStream_t stream) {
    const float* x  = (const float*)d_in[0];
    const float* W1 = (const float*)d_in[1];
    const float* b1 = (const float*)d_in[2];
    const float* W2 = (const float*)d_in[3];
    const float* b2 = (const float*)d_in[4];
    const float* ew = (const float*)d_in[5];
    const int* src  = (const int*)d_in[6];
    const int* dst  = (const int*)d_in[7];
    float* out = (float*)d_out;

    char* ws = (char*)d_ws;
    bf16*  h0      = (bf16*)(ws + 0);              // 25,600,000
    bf16*  h       = (bf16*)(ws + 25600000);       // 25,600,000
    bf16*  g       = (bf16*)(ws + 51200000);       // NN*NC*2 = 3,200,000
    int*   row_off = (int*)(ws + 54400000);        // (NN+1)*4 = 400,004
    int*   bucket_cursor = (int*)(ws + 54800016);  // 1,564
    int*   bucket_base   = (int*)(ws + 54801584);  // 1,568
    int2*  edges   = (int2*)(ws + 54803168);       // EE*8 + 128 pad = 25,600,128
    bf16*  W1T     = (bf16*)(ws + 80403296);       // 65,536 -> end 80,468,832
    // staged aliases h0 + low part of h: dead before k_gemm1 writes h0
    int2*  staged  = (int2*)(ws + 0);              // NBKT*BCAP*8 = 30,028,800

    // CSR build
    k_init<<<1, 512, 0, stream>>>(bucket_cursor, edges);
    k_bucket<<<(EE + CHUNK - 1) / CHUNK, 512, 0, stream>>>(src, dst, ew, bucket_cursor, staged);
    k_bscan<<<1, 512, 0, stream>>>(bucket_cursor, bucket_base, row_off);
    k_sort<<<NBKT, 512, 0, stream>>>(staged, bucket_cursor, bucket_base, row_off, edges);

    // layer 1
    k_cvtW1<<<(NF * NH) / 256, 256, 0, stream>>>(W1, W1T);
    k_gemm1<<<(NN + 63) / 64, 256, 0, stream>>>(x, W1T, h0);
    k_spmm1<<<NN / 4, 256, 0, stream>>>(row_off, edges, h0, b1, h);

    // layer 2
    k_gemm2<<<(NN + 255) / 256, 256, 0, stream>>>(h, W2, g);
    k_spmm2<<<NN / 4, 256, 0, stream>>>(row_off, edges, g, b2, out);
}